// Round 5
// baseline (374.473 us; speedup 1.0000x reference)
//
#include <hip/hip_runtime.h>
#include <cstdint>

#define T 512
#define B 256
#define D 128
#define H 256
#define DH 384
#define INV2PI 0.15915494309189535f

typedef float f32x4 __attribute__((ext_vector_type(4)));

// ws float offsets
#define WHS_OFF 0          // 32 floats
#define HXS_OFF 64         // T*B = 131072 floats
#define CXF_OFF 131136     // 256 floats
#define ZX_OFF  132096     // aligned start of zx
#define ZX_FLOATS (T * B * 32)  // 4194304

// ---------------- K0: whs[g*8+q] = sum_h W[q, 128+h] / (2*pi) ----------------
__global__ __launch_bounds__(256) void k0_whs(const float* __restrict__ Wf, const float* __restrict__ Wi,
                                              const float* __restrict__ Wu, const float* __restrict__ Wo,
                                              float* __restrict__ whs) {
  int tid = threadIdx.x;
  int g = tid >> 6, r = tid & 63, q = r >> 3, part = r & 7;
  const float* W = (g == 0) ? Wf : (g == 1) ? Wi : (g == 2) ? Wu : Wo;
  const float* p = W + q * DH + D + part * 32;
  float s = 0.f;
#pragma unroll
  for (int h = 0; h < 32; ++h) s += p[h];
  s += __shfl_xor(s, 1);
  s += __shfl_xor(s, 2);
  s += __shfl_xor(s, 4);
  if (part == 0) whs[g * 8 + q] = s * INV2PI;
}

// ---------------- K1: zx[(t*B+b)*32 + g*8 + q] = (x . W[g][q,:128] + b + p)/2pi ------------
__global__ __launch_bounds__(128) void k1_gemm(const float* __restrict__ x,
    const float* __restrict__ Wf, const float* __restrict__ bf, const float* __restrict__ pf,
    const float* __restrict__ Wi, const float* __restrict__ bi, const float* __restrict__ pi,
    const float* __restrict__ Wu, const float* __restrict__ bu, const float* __restrict__ pu,
    const float* __restrict__ Wo, const float* __restrict__ bo, const float* __restrict__ po,
    float* __restrict__ zx) {
  __shared__ float wl[28 * 128];
  __shared__ float offs[32];
  int tid = threadIdx.x;
  const float* Ws[4] = {Wf, Wi, Wu, Wo};
  const float* bs[4] = {bf, bi, bu, bo};
  const float* ps[4] = {pf, pi, pu, po};
#pragma unroll
  for (int g = 0; g < 4; ++g)
    for (int i = tid; i < 896; i += 128) {
      int q = i >> 7, d = i & 127;
      wl[g * 896 + i] = Ws[g][(q + 1) * DH + d] * INV2PI;
    }
  if (tid < 32) {
    int g = tid >> 3, q = tid & 7;
    offs[tid] = (bs[g][q] + ps[g][q]) * INV2PI;
  }
  __syncthreads();

  int row0 = blockIdx.x * 512 + tid;
  const float4* x4 = (const float4*)x;
  const float4* wl4 = (const float4*)wl;

  float acc0[28], acc1[28], acc2[28], acc3[28];
#pragma unroll
  for (int r = 0; r < 28; ++r) acc0[r] = acc1[r] = acc2[r] = acc3[r] = 0.f;

  for (int k = 0; k < 32; ++k) {
    float4 xv0 = x4[(size_t)row0 * 32 + k];
    float4 xv1 = x4[(size_t)row0 * 32 + 4096 + k];
    float4 xv2 = x4[(size_t)row0 * 32 + 8192 + k];
    float4 xv3 = x4[(size_t)row0 * 32 + 12288 + k];
#pragma unroll
    for (int r = 0; r < 28; ++r) {
      float4 wv = wl4[r * 32 + k];
      acc0[r] = fmaf(xv0.x, wv.x, fmaf(xv0.y, wv.y, fmaf(xv0.z, wv.z, fmaf(xv0.w, wv.w, acc0[r]))));
      acc1[r] = fmaf(xv1.x, wv.x, fmaf(xv1.y, wv.y, fmaf(xv1.z, wv.z, fmaf(xv1.w, wv.w, acc1[r]))));
      acc2[r] = fmaf(xv2.x, wv.x, fmaf(xv2.y, wv.y, fmaf(xv2.z, wv.z, fmaf(xv2.w, wv.w, acc2[r]))));
      acc3[r] = fmaf(xv3.x, wv.x, fmaf(xv3.y, wv.y, fmaf(xv3.z, wv.z, fmaf(xv3.w, wv.w, acc3[r]))));
    }
  }

#define WROW(ACC, M)                                                                     \
  {                                                                                      \
    float4* zo = (float4*)(zx + (size_t)(row0 + (M)*128) * 32);                          \
    _Pragma("unroll") for (int g = 0; g < 4; ++g) {                                      \
      zo[g * 2 + 0] = make_float4(0.f, ACC[g * 7 + 0] + offs[g * 8 + 1],                 \
                                  ACC[g * 7 + 1] + offs[g * 8 + 2],                      \
                                  ACC[g * 7 + 2] + offs[g * 8 + 3]);                     \
      zo[g * 2 + 1] = make_float4(ACC[g * 7 + 3] + offs[g * 8 + 4],                      \
                                  ACC[g * 7 + 4] + offs[g * 8 + 5],                      \
                                  ACC[g * 7 + 5] + offs[g * 8 + 6],                      \
                                  ACC[g * 7 + 6] + offs[g * 8 + 7]);                     \
    }                                                                                    \
  }
  WROW(acc0, 0) WROW(acc1, 1) WROW(acc2, 2) WROW(acc3, 3)
#undef WROW
}

// ---------------- K2: sequential scan; Pade-tanh gates (3 TRANS on chain, not 5) --------
__device__ __forceinline__ float qcos(float x) {
  return __builtin_amdgcn_cosf(__builtin_amdgcn_fractf(x));
}
#define QBCAST(v, CTRL) __int_as_float(__builtin_amdgcn_mov_dpp(__float_as_int(v), (CTRL), 0xF, 0xF, true))
#define ASMBAR asm volatile("" ::: "memory")

// tanh(x) ~= x*(945+105t+t^2)/(945+420t+15t^2), t=x^2  (err<=5e-5 for |x|<=2.2)
// One scan step; consumes z regs Z0,Z1 (pure VALU otherwise).
#define STEP(S, Z0, Z1)                                                    \
  {                                                                        \
    float c1 = qcos(fmaf(hx, w0, Z0[1]));                                  \
    float c2 = qcos(fmaf(hx, w1, Z0[2]));                                  \
    float c3 = qcos(fmaf(hx, w2, Z0[3]));                                  \
    float c4 = qcos(fmaf(hx, w3, Z1[0]));                                  \
    float c5 = qcos(fmaf(hx, w4, Z1[1]));                                  \
    float c6 = qcos(fmaf(hx, w5, Z1[2]));                                  \
    float c7 = qcos(fmaf(hx, w6, Z1[3])) * sgate;                          \
    float y = ((c1 * c2) * (c3 * c4)) * ((c5 * c6) * c7);                  \
    float t = y * y;                                                       \
    float nn = fmaf(t, 105.f + t, 945.f);                                  \
    float dd = fmaf(t, fmaf(15.f, t, 420.f), 945.f);                       \
    float th = (y * nn) * __builtin_amdgcn_rcpf(dd);                       \
    float val = fmaf(th, sgate, gb);                                       \
    float fv = QBCAST(val, 0x00);                                          \
    float iv = QBCAST(val, 0x55);                                          \
    float gv = QBCAST(val, 0xAA);                                          \
    float ov = QBCAST(val, 0xFF);                                          \
    cx = fmaf(fv, cx, iv * gv);                                            \
    float t2 = cx * cx;                                                    \
    float n2 = fmaf(t2, 105.f + t2, 945.f);                                \
    float d2 = fmaf(t2, fmaf(15.f, t2, 420.f), 945.f);                     \
    hx = ov * ((cx * n2) * __builtin_amdgcn_rcpf(d2));                     \
    h##S = hx;                                                             \
  }

// load one 8-step group (16 f32x4) into bank regs AP#/BP#
#define LOADG(AP, BP, KT)                                                  \
  {                                                                        \
    const f32x4* gp = zp + (size_t)(KT) * 16384;                           \
    AP##0 = gp[0];     BP##0 = gp[1];                                      \
    AP##1 = gp[2048];  BP##1 = gp[2049];                                   \
    AP##2 = gp[4096];  BP##2 = gp[4097];                                   \
    AP##3 = gp[6144];  BP##3 = gp[6145];                                   \
    AP##4 = gp[8192];  BP##4 = gp[8193];                                   \
    AP##5 = gp[10240]; BP##5 = gp[10241];                                  \
    AP##6 = gp[12288]; BP##6 = gp[12289];                                  \
    AP##7 = gp[14336]; BP##7 = gp[14337];                                  \
  }                                                                        \
  ASMBAR;

#define STEPS(AP, BP)                                                      \
  STEP(0, AP##0, BP##0) STEP(1, AP##1, BP##1) STEP(2, AP##2, BP##2)        \
  STEP(3, AP##3, BP##3) STEP(4, AP##4, BP##4) STEP(5, AP##5, BP##5)        \
  STEP(6, AP##6, BP##6) STEP(7, AP##7, BP##7)

#define STOREH(KT)                                                         \
  if (g == 0) {                                                            \
    float* hp = hxs + (size_t)(KT) * 8 * B + b;                            \
    hp[0 * B] = h0; hp[1 * B] = h1; hp[2 * B] = h2; hp[3 * B] = h3;        \
    hp[4 * B] = h4; hp[5 * B] = h5; hp[6 * B] = h6; hp[7 * B] = h7;        \
  }

__global__ __launch_bounds__(64) void k2_scan(const float* __restrict__ zx, const float* __restrict__ whs,
                                              const float* __restrict__ hx0, const float* __restrict__ cx0,
                                              float* __restrict__ hxs, float* __restrict__ cxf) {
  int tid = threadIdx.x;
  int g = tid & 3;
  int b = blockIdx.x * 16 + (tid >> 2);

  float w0 = whs[g * 8 + 1], w1 = whs[g * 8 + 2], w2 = whs[g * 8 + 3], w3 = whs[g * 8 + 4];
  float w4 = whs[g * 8 + 5], w5 = whs[g * 8 + 6], w6 = whs[g * 8 + 7];
  bool isU = (g == 2);
  float sgate = isU ? 1.f : 0.5f;  // tanh(pr) for u-gate; 0.5+0.5*tanh(pr/2) = sigmoid(pr) else
  float gb = isU ? 0.f : 0.5f;

  float hx = hx0[(size_t)b * H];
  float cx = cx0[(size_t)b * H];

  const f32x4* zp = (const f32x4*)zx + ((size_t)b * 8 + (size_t)g * 2);

  f32x4 aA0, aA1, aA2, aA3, aA4, aA5, aA6, aA7, aB0, aB1, aB2, aB3, aB4, aB5, aB6, aB7;
  f32x4 bA0, bA1, bA2, bA3, bA4, bA5, bA6, bA7, bB0, bB1, bB2, bB3, bB4, bB5, bB6, bB7;
  float h0, h1, h2, h3, h4, h5, h6, h7;

  // prologue: group 0 -> bank a, group 1 -> bank b
  LOADG(aA, aB, 0)
  LOADG(bA, bB, 1)
  asm volatile("s_waitcnt vmcnt(16)" ::: "memory");  // group 0 complete, group 1 in flight
  STEPS(aA, aB)
  STOREH(0)

  for (int kt = 1; kt < 63; kt += 2) {
    // group kt (odd -> bank b); prefetch kt+1 into bank a
    asm volatile("s_waitcnt vmcnt(8)" ::: "memory");  // 8 newest = stores of group kt-1
    LOADG(aA, aB, kt + 1)
    STEPS(bA, bB)
    STOREH(kt)
    // group kt+1 (even -> bank a); prefetch kt+2 into bank b
    asm volatile("s_waitcnt vmcnt(8)" ::: "memory");
    LOADG(bA, bB, kt + 2)
    STEPS(aA, aB)
    STOREH(kt + 1)
  }
  // group 63 (bank b), no prefetch
  asm volatile("s_waitcnt vmcnt(8)" ::: "memory");
  STEPS(bA, bB)
  STOREH(63)

  if (g == 0) cxf[b] = cx;
}

// ---------------- K3: broadcast hx over H into the full output ----------------
__global__ __launch_bounds__(256) void k3_bcast(const float* __restrict__ hxs, const float* __restrict__ cxf,
                                                float* __restrict__ out) {
  const int TBH4 = (T * B * H) / 4;  // 8388608
  const int BH4 = (B * H) / 4;       // 16384
  const int N4 = TBH4 + 2 * BH4;
  f32x4* out4 = (f32x4*)out;
  int stride = gridDim.x * blockDim.x;
  for (int i = blockIdx.x * blockDim.x + threadIdx.x; i < N4; i += stride) {
    float v;
    if (i < TBH4)            v = hxs[i >> 6];
    else if (i < TBH4 + BH4) v = hxs[(T - 1) * B + ((i - TBH4) >> 6)];
    else                     v = cxf[(i - TBH4 - BH4) >> 6];
    f32x4 pv = {v, v, v, v};
    __builtin_nontemporal_store(pv, &out4[i]);
  }
}

extern "C" void kernel_launch(void* const* d_in, const int* in_sizes, int n_in,
                              void* d_out, int out_size, void* d_ws, size_t ws_size,
                              hipStream_t stream) {
  const float* x   = (const float*)d_in[0];
  const float* hx0 = (const float*)d_in[1];
  const float* cx0 = (const float*)d_in[2];
  const float* Wf = (const float*)d_in[3];  const float* bf = (const float*)d_in[4];  const float* pf = (const float*)d_in[5];
  const float* Wi = (const float*)d_in[6];  const float* bi = (const float*)d_in[7];  const float* pi = (const float*)d_in[8];
  const float* Wu = (const float*)d_in[9];  const float* bu = (const float*)d_in[10]; const float* pu = (const float*)d_in[11];
  const float* Wo = (const float*)d_in[12]; const float* bo = (const float*)d_in[13]; const float* po = (const float*)d_in[14];

  float* wsf = (float*)d_ws;
  float* whs = wsf + WHS_OFF;
  float* hxs = wsf + HXS_OFF;
  float* cxf = wsf + CXF_OFF;
  float* out = (float*)d_out;
  float* zx = (ws_size >= (size_t)(ZX_OFF + ZX_FLOATS) * sizeof(float))
                  ? (wsf + ZX_OFF)
                  : (out + ((size_t)out_size - ZX_FLOATS));

  hipLaunchKernelGGL(k0_whs, dim3(1), dim3(256), 0, stream, Wf, Wi, Wu, Wo, whs);
  hipLaunchKernelGGL(k1_gemm, dim3(256), dim3(128), 0, stream,
                     x, Wf, bf, pf, Wi, bi, pi, Wu, bu, pu, Wo, bo, po, zx);
  hipLaunchKernelGGL(k2_scan, dim3(16), dim3(64), 0, stream, zx, whs, hx0, cx0, hxs, cxf);
  hipLaunchKernelGGL(k3_bcast, dim3(4096), dim3(256), 0, stream, hxs, cxf, out);
}

// Round 8
// 371.446 us; speedup vs baseline: 1.0081x; 1.0081x over previous
//
#include <hip/hip_runtime.h>
#include <cstdint>

#define T 512
#define B 256
#define D 128
#define H 256
#define DH 384
#define INV2PI 0.15915494309189535f

typedef float f32x4 __attribute__((ext_vector_type(4)));

// ws float offsets
#define WHS_OFF 0          // 32 floats
#define HXS_OFF 64         // T*B = 131072 floats
#define CXF_OFF 131136     // 256 floats
#define ZX_OFF  132096     // aligned start of zx
#define ZX_FLOATS (T * B * 32)  // 4194304

// ---------------- K1: zx[(t*B+b)*32 + g*8 + q] = (x . W[g][q,:128] + b + p)/2pi ------------
// Block 0 additionally computes whs[g*8+q] = sum_h W[q,128+h]/2pi (k0 folded in).
__global__ __launch_bounds__(128) void k1_gemm(const float* __restrict__ x,
    const float* __restrict__ Wf, const float* __restrict__ bf, const float* __restrict__ pf,
    const float* __restrict__ Wi, const float* __restrict__ bi, const float* __restrict__ pi,
    const float* __restrict__ Wu, const float* __restrict__ bu, const float* __restrict__ pu,
    const float* __restrict__ Wo, const float* __restrict__ bo, const float* __restrict__ po,
    float* __restrict__ zx, float* __restrict__ whs) {
  __shared__ float wl[28 * 128];
  __shared__ float offs[32];
  int tid = threadIdx.x;
  const float* Ws[4] = {Wf, Wi, Wu, Wo};
  const float* bs[4] = {bf, bi, bu, bo};
  const float* ps[4] = {pf, pi, pu, po};
#pragma unroll
  for (int g = 0; g < 4; ++g)
    for (int i = tid; i < 896; i += 128) {
      int q = i >> 7, d = i & 127;
      wl[g * 896 + i] = Ws[g][(q + 1) * DH + d] * INV2PI;
    }
  if (tid < 32) {
    int g = tid >> 3, q = tid & 7;
    offs[tid] = (bs[g][q] + ps[g][q]) * INV2PI;
  }
  __syncthreads();

  int row0 = blockIdx.x * 512 + tid;
  const float4* x4 = (const float4*)x;
  const float4* wl4 = (const float4*)wl;

  float acc0[28], acc1[28], acc2[28], acc3[28];
#pragma unroll
  for (int r = 0; r < 28; ++r) acc0[r] = acc1[r] = acc2[r] = acc3[r] = 0.f;

  for (int k = 0; k < 32; ++k) {
    float4 xv0 = x4[(size_t)row0 * 32 + k];
    float4 xv1 = x4[(size_t)row0 * 32 + 4096 + k];
    float4 xv2 = x4[(size_t)row0 * 32 + 8192 + k];
    float4 xv3 = x4[(size_t)row0 * 32 + 12288 + k];
#pragma unroll
    for (int r = 0; r < 28; ++r) {
      float4 wv = wl4[r * 32 + k];
      acc0[r] = fmaf(xv0.x, wv.x, fmaf(xv0.y, wv.y, fmaf(xv0.z, wv.z, fmaf(xv0.w, wv.w, acc0[r]))));
      acc1[r] = fmaf(xv1.x, wv.x, fmaf(xv1.y, wv.y, fmaf(xv1.z, wv.z, fmaf(xv1.w, wv.w, acc1[r]))));
      acc2[r] = fmaf(xv2.x, wv.x, fmaf(xv2.y, wv.y, fmaf(xv2.z, wv.z, fmaf(xv2.w, wv.w, acc2[r]))));
      acc3[r] = fmaf(xv3.x, wv.x, fmaf(xv3.y, wv.y, fmaf(xv3.z, wv.z, fmaf(xv3.w, wv.w, acc3[r]))));
    }
  }

#define WROW(ACC, M)                                                                     \
  {                                                                                      \
    float4* zo = (float4*)(zx + (size_t)(row0 + (M)*128) * 32);                          \
    _Pragma("unroll") for (int g = 0; g < 4; ++g) {                                      \
      zo[g * 2 + 0] = make_float4(0.f, ACC[g * 7 + 0] + offs[g * 8 + 1],                 \
                                  ACC[g * 7 + 1] + offs[g * 8 + 2],                      \
                                  ACC[g * 7 + 2] + offs[g * 8 + 3]);                     \
      zo[g * 2 + 1] = make_float4(ACC[g * 7 + 3] + offs[g * 8 + 4],                      \
                                  ACC[g * 7 + 4] + offs[g * 8 + 5],                      \
                                  ACC[g * 7 + 5] + offs[g * 8 + 6],                      \
                                  ACC[g * 7 + 6] + offs[g * 8 + 7]);                     \
    }                                                                                    \
  }
  WROW(acc0, 0) WROW(acc1, 1) WROW(acc2, 2) WROW(acc3, 3)
#undef WROW

  // folded k0: block 0 computes whs
  if (blockIdx.x == 0 && tid < 32) {
    int g = tid >> 3, q = tid & 7;
    const f32x4* wp = (const f32x4*)(Ws[g] + q * DH + D);
    f32x4 s4 = {0.f, 0.f, 0.f, 0.f};
#pragma unroll
    for (int h = 0; h < 64; ++h) s4 += wp[h];
    whs[tid] = (s4[0] + s4[1] + s4[2] + s4[3]) * INV2PI;
  }
}

// ---------------- K2: sequential scan; Pade-tanh gates; reg double-bank prefetch --------
__device__ __forceinline__ float qcos(float x) {
  return __builtin_amdgcn_cosf(__builtin_amdgcn_fractf(x));
}
#define QBCAST(v, CTRL) __int_as_float(__builtin_amdgcn_mov_dpp(__float_as_int(v), (CTRL), 0xF, 0xF, true))
#define ASMBAR asm volatile("" ::: "memory")

// tanh(x) ~= x*(945+105t+t^2)/(945+420t+15t^2), t=x^2  (err<=5e-5 for |x|<=2.2)
#define STEP(S, Z0, Z1)                                                    \
  {                                                                        \
    float c1 = qcos(fmaf(hx, w0, Z0[1]));                                  \
    float c2 = qcos(fmaf(hx, w1, Z0[2]));                                  \
    float c3 = qcos(fmaf(hx, w2, Z0[3]));                                  \
    float c4 = qcos(fmaf(hx, w3, Z1[0]));                                  \
    float c5 = qcos(fmaf(hx, w4, Z1[1]));                                  \
    float c6 = qcos(fmaf(hx, w5, Z1[2]));                                  \
    float c7 = qcos(fmaf(hx, w6, Z1[3])) * sgate;                          \
    float y = ((c1 * c2) * (c3 * c4)) * ((c5 * c6) * c7);                  \
    float t = y * y;                                                       \
    float nn = fmaf(t, 105.f + t, 945.f);                                  \
    float dd = fmaf(t, fmaf(15.f, t, 420.f), 945.f);                       \
    float th = (y * nn) * __builtin_amdgcn_rcpf(dd);                       \
    float val = fmaf(th, sgate, gb);                                       \
    float fv = QBCAST(val, 0x00);                                          \
    float iv = QBCAST(val, 0x55);                                          \
    float gv = QBCAST(val, 0xAA);                                          \
    float ov = QBCAST(val, 0xFF);                                          \
    cx = fmaf(fv, cx, iv * gv);                                            \
    float t2 = cx * cx;                                                    \
    float n2 = fmaf(t2, 105.f + t2, 945.f);                                \
    float d2 = fmaf(t2, fmaf(15.f, t2, 420.f), 945.f);                     \
    hx = ov * ((cx * n2) * __builtin_amdgcn_rcpf(d2));                     \
    h##S = hx;                                                             \
  }

#define LOADG(AP, BP, KT)                                                  \
  {                                                                        \
    const f32x4* gp = zp + (size_t)(KT) * 16384;                           \
    AP##0 = gp[0];     BP##0 = gp[1];                                      \
    AP##1 = gp[2048];  BP##1 = gp[2049];                                   \
    AP##2 = gp[4096];  BP##2 = gp[4097];                                   \
    AP##3 = gp[6144];  BP##3 = gp[6145];                                   \
    AP##4 = gp[8192];  BP##4 = gp[8193];                                   \
    AP##5 = gp[10240]; BP##5 = gp[10241];                                  \
    AP##6 = gp[12288]; BP##6 = gp[12289];                                  \
    AP##7 = gp[14336]; BP##7 = gp[14337];                                  \
  }                                                                        \
  ASMBAR;

#define STEPS(AP, BP)                                                      \
  STEP(0, AP##0, BP##0) STEP(1, AP##1, BP##1) STEP(2, AP##2, BP##2)        \
  STEP(3, AP##3, BP##3) STEP(4, AP##4, BP##4) STEP(5, AP##5, BP##5)        \
  STEP(6, AP##6, BP##6) STEP(7, AP##7, BP##7)

#define STOREH(KT)                                                         \
  if (g == 0) {                                                            \
    float* hp = hxs + (size_t)(KT) * 8 * B + b;                            \
    hp[0 * B] = h0; hp[1 * B] = h1; hp[2 * B] = h2; hp[3 * B] = h3;        \
    hp[4 * B] = h4; hp[5 * B] = h5; hp[6 * B] = h6; hp[7 * B] = h7;        \
  }

__global__ __launch_bounds__(64, 1) void k2_scan(const float* __restrict__ zx, const float* __restrict__ whs,
                                                 const float* __restrict__ hx0, const float* __restrict__ cx0,
                                                 float* __restrict__ hxs, float* __restrict__ cxf) {
  int tid = threadIdx.x;
  int g = tid & 3;
  int b = blockIdx.x * 16 + (tid >> 2);

  float w0 = whs[g * 8 + 1], w1 = whs[g * 8 + 2], w2 = whs[g * 8 + 3], w3 = whs[g * 8 + 4];
  float w4 = whs[g * 8 + 5], w5 = whs[g * 8 + 6], w6 = whs[g * 8 + 7];
  bool isU = (g == 2);
  float sgate = isU ? 1.f : 0.5f;  // tanh(pr) for u-gate; 0.5+0.5*tanh(pr/2) = sigmoid(pr) else
  float gb = isU ? 0.f : 0.5f;

  float hx = hx0[(size_t)b * H];
  float cx = cx0[(size_t)b * H];

  const f32x4* zp = (const f32x4*)zx + ((size_t)b * 8 + (size_t)g * 2);

  f32x4 aA0, aA1, aA2, aA3, aA4, aA5, aA6, aA7, aB0, aB1, aB2, aB3, aB4, aB5, aB6, aB7;
  f32x4 bA0, bA1, bA2, bA3, bA4, bA5, bA6, bA7, bB0, bB1, bB2, bB3, bB4, bB5, bB6, bB7;
  float h0, h1, h2, h3, h4, h5, h6, h7;

  // prologue: group 0 -> bank a, group 1 -> bank b
  LOADG(aA, aB, 0)
  LOADG(bA, bB, 1)
  asm volatile("s_waitcnt vmcnt(16)" ::: "memory");  // group 0 complete, group 1 in flight
  STEPS(aA, aB)
  STOREH(0)

  for (int kt = 1; kt < 63; kt += 2) {
    asm volatile("s_waitcnt vmcnt(8)" ::: "memory");
    LOADG(aA, aB, kt + 1)
    STEPS(bA, bB)
    STOREH(kt)
    asm volatile("s_waitcnt vmcnt(8)" ::: "memory");
    LOADG(bA, bB, kt + 2)
    STEPS(aA, aB)
    STOREH(kt + 1)
  }
  asm volatile("s_waitcnt vmcnt(8)" ::: "memory");
  STEPS(bA, bB)
  STOREH(63)

  if (g == 0) cxf[b] = cx;
}

// ---------------- K3: broadcast hx over H into the full output ----------------
__global__ __launch_bounds__(256) void k3_bcast(const float* __restrict__ hxs, const float* __restrict__ cxf,
                                                float* __restrict__ out) {
  const int TBH4 = (T * B * H) / 4;  // 8388608
  const int BH4 = (B * H) / 4;       // 16384
  const int N4 = TBH4 + 2 * BH4;
  f32x4* out4 = (f32x4*)out;
  int stride = gridDim.x * blockDim.x;
  for (int i = blockIdx.x * blockDim.x + threadIdx.x; i < N4; i += stride) {
    float v;
    if (i < TBH4)            v = hxs[i >> 6];
    else if (i < TBH4 + BH4) v = hxs[(T - 1) * B + ((i - TBH4) >> 6)];
    else                     v = cxf[(i - TBH4 - BH4) >> 6];
    f32x4 pv = {v, v, v, v};
    __builtin_nontemporal_store(pv, &out4[i]);
  }
}

extern "C" void kernel_launch(void* const* d_in, const int* in_sizes, int n_in,
                              void* d_out, int out_size, void* d_ws, size_t ws_size,
                              hipStream_t stream) {
  const float* x   = (const float*)d_in[0];
  const float* hx0 = (const float*)d_in[1];
  const float* cx0 = (const float*)d_in[2];
  const float* Wf = (const float*)d_in[3];  const float* bf = (const float*)d_in[4];  const float* pf = (const float*)d_in[5];
  const float* Wi = (const float*)d_in[6];  const float* bi = (const float*)d_in[7];  const float* pi = (const float*)d_in[8];
  const float* Wu = (const float*)d_in[9];  const float* bu = (const float*)d_in[10]; const float* pu = (const float*)d_in[11];
  const float* Wo = (const float*)d_in[12]; const float* bo = (const float*)d_in[13]; const float* po = (const float*)d_in[14];

  float* wsf = (float*)d_ws;
  float* whs = wsf + WHS_OFF;
  float* hxs = wsf + HXS_OFF;
  float* cxf = wsf + CXF_OFF;
  float* out = (float*)d_out;
  float* zx = (ws_size >= (size_t)(ZX_OFF + ZX_FLOATS) * sizeof(float))
                  ? (wsf + ZX_OFF)
                  : (out + ((size_t)out_size - ZX_FLOATS));

  hipLaunchKernelGGL(k1_gemm, dim3(256), dim3(128), 0, stream,
                     x, Wf, bf, pf, Wi, bi, pi, Wu, bu, pu, Wo, bo, po, zx, whs);
  hipLaunchKernelGGL(k2_scan, dim3(16), dim3(64), 0, stream, zx, whs, hx0, cx0, hxs, cxf);
  hipLaunchKernelGGL(k3_bcast, dim3(4096), dim3(256), 0, stream, hxs, cxf, out);
}